// Round 8
// baseline (3268.336 us; speedup 1.0000x reference)
//
#include <hip/hip_runtime.h>
#include <cstdint>
#include <cstddef>

#define THREADS 256

typedef _Float16 f16x8 __attribute__((ext_vector_type(8)));
typedef _Float16 f16x4 __attribute__((ext_vector_type(4)));
typedef _Float16 f16x2 __attribute__((ext_vector_type(2)));
typedef float f32x4 __attribute__((ext_vector_type(4)));
typedef float f32x8 __attribute__((ext_vector_type(8)));

__device__ __forceinline__ void gll16(const void* g, void* l) {
    __builtin_amdgcn_global_load_lds(
        (const __attribute__((address_space(1))) unsigned int*)g,
        (__attribute__((address_space(3))) unsigned int*)l, 16, 0, 0);
}

// ---------------------------------------------------------------------------
// Weight pack (old format, for scale/comb convs):
// fp32 OIHW -> fp16 [tap][cc][u(4)][co][8]  (zero-fill ci>=Cin)
// ---------------------------------------------------------------------------
__global__ void pack_w16_kernel(const float* __restrict__ w, _Float16* __restrict__ wp,
                                int Cin, int Cout, int CC)
{
    int idx = blockIdx.x * THREADS + threadIdx.x;
    int total = Cout * CC * 4;
    if (idx >= total) return;
    int u = idx & 3;
    int cc = (idx >> 2) % CC;
    int co = (idx >> 2) / CC;
    int ci0 = cc * 32 + u * 8;
    for (int tap = 0; tap < 9; ++tap) {
        f16x8 v;
#pragma unroll
        for (int j = 0; j < 8; ++j) {
            int ci = ci0 + j;
            v[j] = (ci < Cin) ? (_Float16)w[((size_t)co * Cin + ci) * 9 + tap] : (_Float16)0.f;
        }
        *reinterpret_cast<f16x8*>(wp + ((((size_t)tap * CC + cc) * 4 + u) * Cout + co) * 8) = v;
    }
}

// ---------------------------------------------------------------------------
// Head-GEMM weight pack: fp32 OIHW -> fp16 [kstep][gy(2)][chunk 2048][8]
// K linearized tap-major (k = tap*Cin + ci), 64-wide K-steps.
// Bank-swizzle baked in: chunk (r*8+kc) holds k-slice (kc ^ (r&7)).
// ---------------------------------------------------------------------------
__global__ void pack_whead_kernel(const float* __restrict__ w, _Float16* __restrict__ wp,
                                  int Cin)
{
    const int NSTEP = 9 * (Cin / 64);
    int idx = blockIdx.x * THREADS + threadIdx.x;
    int total = 512 * NSTEP * 8;
    if (idx >= total) return;
    int kc = idx & 7;
    int t = (idx >> 3) % NSTEP;
    int co = (idx >> 3) / NSTEP;
    int gy = co >> 8;
    int r = co & 255;
    int kcs = kc ^ (r & 7);
    int k = t * 64 + kcs * 8;
    int tap = k / Cin;
    int cib = k - tap * Cin;
    f16x8 v;
#pragma unroll
    for (int j = 0; j < 8; ++j)
        v[j] = (_Float16)w[((size_t)co * Cin + cib + j) * 9 + tap];
    *reinterpret_cast<f16x8*>(wp + ((size_t)(t * 2 + gy) * 2048 + r * 8 + kc) * 8) = v;
}

__global__ void zerows_kernel(float* __restrict__ p)
{
    p[blockIdx.x * THREADS + threadIdx.x] = 0.f;
}

// ---------------------------------------------------------------------------
// NCHW fp32 -> NHWC fp16 transpose. Tile: 32 ci x 64 px. Grid (HW/64, C/32, N).
// ---------------------------------------------------------------------------
__global__ __launch_bounds__(256)
void t_kernel(const float* __restrict__ in, _Float16* __restrict__ out, int C, int HW)
{
    __shared__ _Float16 tile[64 * 32];
    const int n = blockIdx.z;
    const int c0 = blockIdx.y * 32;
    const int p0 = blockIdx.x * 64;
    const int tid = threadIdx.x;
    {
        int ci = tid >> 3;
        int j8 = (tid & 7) * 8;
        f32x8 v = *reinterpret_cast<const f32x8*>(in + ((size_t)n * C + c0 + ci) * HW + p0 + j8);
#pragma unroll
        for (int j = 0; j < 8; ++j)
            tile[(j8 + j) * 32 + ci] = (_Float16)v[j];
    }
    __syncthreads();
    {
        int px = tid >> 2;
        int u = tid & 3;
        f16x8 v = *reinterpret_cast<const f16x8*>(&tile[px * 32 + u * 8]);
        *reinterpret_cast<f16x8*>(out + ((size_t)n * HW + p0 + px) * C + c0 + u * 8) = v;
    }
}

// ---------------------------------------------------------------------------
// Old unified conv (kept for scale heads + comb conv). See round-4 comments.
// ---------------------------------------------------------------------------
template<int INF32, int OUTMODE, int CC>
__global__ __launch_bounds__(512, 4)
void convu_kernel(const void* __restrict__ inv, const _Float16* __restrict__ wp,
                  const float* __restrict__ bias, const int* __restrict__ msk,
                  void* __restrict__ outp, int Cout, int H, int W,
                  int inCst, int outCst, int useMask)
{
    __shared__ _Float16 Xs[2 * 1344 * 8];

    const int tid = threadIdx.x;
    const int lane = tid & 63;
    const int wave = tid >> 6;
    const int lm = lane & 15;
    const int lu = lane >> 4;
    const int waveco = (wave & 1) * 64;
    const int wrow = (wave >> 1) * 4;
    const int n = blockIdx.z;
    const int co0 = blockIdx.y * 128;
    const int tpr = W >> 4;
    const int tx = blockIdx.x % tpr;
    const int ty = blockIdx.x / tpr;
    const int x0 = tx << 4;
    const int y0 = ty << 4;
    const int HW = H * W;

    int soff[3];
#pragma unroll
    for (int t = 0; t < 3; ++t) {
        int s = tid + t * 512;
        int item = s >> 2, u = s & 3;
        int row = item / 18, col = item - row * 18;
        int y = y0 + row - 1, x = x0 + col - 1;
        soff[t] = (s < 1296 && y >= 0 && y < H && x >= 0 && x < W)
                      ? ((n * HW + y * W + x) * inCst + u * 8) : -1;
    }

    f32x4 acc[4][4];
#pragma unroll
    for (int m = 0; m < 4; ++m)
#pragma unroll
        for (int nf = 0; nf < 4; ++nf)
            acc[m][nf] = (f32x4){0.f, 0.f, 0.f, 0.f};

    const size_t tstride = (size_t)CC * 4 * Cout * 8;
    f32x8 rr[3];

    if (INF32 == 0) {
        const _Float16* src = (const _Float16*)inv;
#pragma unroll
        for (int t = 0; t < 3; ++t) {
            int s = tid + t * 512;
            if (s < 1296 && soff[t] < 0) {
                *reinterpret_cast<f16x8*>(&Xs[s * 8]) = (f16x8){};
                *reinterpret_cast<f16x8*>(&Xs[(1344 + s) * 8]) = (f16x8){};
            }
        }
#pragma unroll
        for (int t = 0; t < 3; ++t) {
            int s = tid + t * 512;
            if (s < 1296 && soff[t] >= 0)
                gll16(src + soff[t], &Xs[(t * 512 + (tid & ~63)) * 8]);
        }
    } else {
        const float* srcf = (const float*)inv;
#pragma unroll
        for (int t = 0; t < 3; ++t) {
            int s = tid + t * 512;
            rr[t] = (f32x8){};
            if (s < 1296 && soff[t] >= 0)
                rr[t] = *reinterpret_cast<const f32x8*>(srcf + soff[t]);
        }
#pragma unroll
        for (int t = 0; t < 3; ++t) {
            int s = tid + t * 512;
            if (s < 1296) {
                f16x8 h;
#pragma unroll
                for (int j = 0; j < 8; ++j) h[j] = (_Float16)rr[t][j];
                *reinterpret_cast<f16x8*>(&Xs[s * 8]) = h;
            }
        }
    }
    __syncthreads();

    int bsel = 0;
    for (int cc = 0; cc < CC; ++cc) {
        if (cc + 1 < CC) {
            if (INF32 == 0) {
                const _Float16* src = (const _Float16*)inv;
#pragma unroll
                for (int t = 0; t < 3; ++t) {
                    int s = tid + t * 512;
                    if (s < 1296 && soff[t] >= 0)
                        gll16(src + soff[t] + (cc + 1) * 32,
                              &Xs[((bsel ^ 1) * 1344 + t * 512 + (tid & ~63)) * 8]);
                }
            } else {
                const float* srcf = (const float*)inv;
#pragma unroll
                for (int t = 0; t < 3; ++t) {
                    int s = tid + t * 512;
                    rr[t] = (f32x8){};
                    if (s < 1296 && soff[t] >= 0)
                        rr[t] = *reinterpret_cast<const f32x8*>(srcf + soff[t] + (cc + 1) * 32);
                }
            }
        }
        {
            const int xbase = bsel * 1344;
            const _Float16* wb = wp + (((size_t)cc * 4 + lu) * Cout + co0 + waveco + lm) * 8;
#pragma unroll
            for (int tap = 0; tap < 9; ++tap) {
                const int dy = tap / 3, dx = tap % 3;
                const _Float16* wt = wb + (size_t)tap * tstride;
                f16x8 a[4], b[4];
#pragma unroll
                for (int m = 0; m < 4; ++m)
                    a[m] = *reinterpret_cast<const f16x8*>(wt + m * 128);
#pragma unroll
                for (int nf = 0; nf < 4; ++nf) {
                    int slot = ((wrow + nf + dy) * 18 + lm + dx) * 4 + lu;
                    b[nf] = *reinterpret_cast<const f16x8*>(&Xs[(xbase + slot) * 8]);
                }
#pragma unroll
                for (int m = 0; m < 4; ++m)
#pragma unroll
                    for (int nf = 0; nf < 4; ++nf)
                        acc[m][nf] = __builtin_amdgcn_mfma_f32_16x16x32_f16(a[m], b[nf], acc[m][nf], 0, 0, 0);
            }
        }
        if (INF32 == 1 && cc + 1 < CC) {
#pragma unroll
            for (int t = 0; t < 3; ++t) {
                int s = tid + t * 512;
                if (s < 1296) {
                    f16x8 h;
#pragma unroll
                    for (int j = 0; j < 8; ++j) h[j] = (_Float16)rr[t][j];
                    *reinterpret_cast<f16x8*>(&Xs[((bsel ^ 1) * 1344 + s) * 8]) = h;
                }
            }
        }
        __syncthreads();
        bsel ^= 1;
    }

    const int xE = x0 + lm;
    const size_t nHW = (size_t)n * HW;
#pragma unroll
    for (int nf = 0; nf < 4; ++nf) {
        const int y = y0 + wrow + nf;
        float mv = 1.f;
        if (useMask) mv = (msk[nHW + y * W + xE] > 0) ? 1.f : 0.f;
        const size_t pixo = (nHW + (size_t)y * W + xE) * outCst;
#pragma unroll
        for (int m = 0; m < 4; ++m) {
            const int cb = co0 + waveco + m * 16 + lu * 4;
            const f32x4 bv = *reinterpret_cast<const f32x4*>(bias + cb);
            if (OUTMODE == 0) {
                f16x4 h;
#pragma unroll
                for (int r = 0; r < 4; ++r)
                    h[r] = (_Float16)(fmaxf(acc[m][nf][r] + bv[r], 0.f) * mv);
                *reinterpret_cast<f16x4*>((_Float16*)outp + pixo + cb) = h;
            } else if (OUTMODE == 1) {
                f32x4 v;
#pragma unroll
                for (int r = 0; r < 4; ++r)
                    v[r] = fmaxf(acc[m][nf][r] + bv[r], 0.f);
                *reinterpret_cast<f32x4*>((float*)outp + pixo + cb) = v;
            } else {
                f32x4 old = *reinterpret_cast<const f32x4*>((float*)outp + pixo + cb);
#pragma unroll
                for (int r = 0; r < 4; ++r)
                    old[r] += fmaxf(acc[m][nf][r] + bv[r], 0.f);
                *reinterpret_cast<f32x4*>((float*)outp + pixo + cb) = old;
            }
        }
    }
}

// ---------------------------------------------------------------------------
// Head conv as 256x256-tile LDS-staged GEMM (M=512 co, N=px, K=9*CIN).
// 512 thr, 8 waves x (128co x 64px), K-step 64, dbuf 128KB LDS.
// R7: counted-vmcnt pipeline (T3/T4-lite): 2-deep STAGE, s_waitcnt vmcnt(8)
// per iter (vmcnt(0) only at last), raw s_barrier + sched_barrier(0) fences,
// setprio(1) around MFMA cluster (T5), precomputed B-pointers + 36-bit
// in-bounds mask (VALU cut). K-order ci-block-major (L2-hot, from R6).
// ---------------------------------------------------------------------------
template<int CIN>
__global__ __launch_bounds__(512, 1)
void gemm_head_kernel(const _Float16* __restrict__ in,
                      const _Float16* __restrict__ wpk,
                      const float* __restrict__ bias,
                      const int* __restrict__ fg,
                      _Float16* __restrict__ outp,
                      const _Float16* __restrict__ zpage)
{
    constexpr int SPT = CIN / 64;
    constexpr int NT = 9 * SPT;
    __shared__ _Float16 ldsh[65536];   // 128 KB: 2 bufs x (A 32KB + B 32KB)
    char* ldsb = (char*)ldsh;

    // XCD remap: b&7 ~ XCD; each XCD gets both gy of 32 tiles of one image.
    const int b = blockIdx.x;
    const int xcd = b & 7;
    const int r = b >> 3;              // 0..63
    const int img = xcd >> 1;          // 0..3
    const int half = xcd & 1;          // image half (tile rows 0-3 / 4-7)
    const int tile = half * 32 + (r >> 1);
    const int gy = r & 1;
    const int x0 = (tile & 7) << 4;
    const int y0 = (tile >> 3) << 4;

    const int tid = threadIdx.x;
    const int lane = tid & 63;
    const int wave = tid >> 6;
    const int lm = lane & 15;
    const int lu = lane >> 4;
    const int wco = (wave & 1) * 128;
    const int wpx = (wave >> 1) * 64;
    const int co0 = gy * 256;

    const _Float16* bsrc = in + (size_t)img * 16384 * CIN;

    // ---- precomputed staging state ----
    const _Float16* bptr[4];      // center-tap global src per rr
    unsigned long long inbm = 0;  // bit rr*9+tap: tap in-bounds for this rr
    int dstA[4], dstB[4];
#pragma unroll
    for (int rr = 0; rr < 4; ++rr) {
        const int prow = rr * 64 + (tid >> 3);
        const int kc = (tid & 7) ^ (prow & 7);
        const int yy0 = y0 + (prow >> 4);
        const int xx0 = x0 + (prow & 15);
        bptr[rr] = bsrc + (size_t)(yy0 * 128 + xx0) * CIN + kc * 8;
#pragma unroll
        for (int tap = 0; tap < 9; ++tap) {
            const int yy = yy0 + tap / 3 - 1;
            const int xx = xx0 + tap % 3 - 1;
            if ((unsigned)yy < 128u && (unsigned)xx < 128u)
                inbm |= 1ull << (rr * 9 + tap);
        }
        dstA[rr] = (rr * 512 + (tid & ~63)) * 16;
        dstB[rr] = 32768 + (rr * 512 + (tid & ~63)) * 16;
    }

    auto STAGE = [&](int sid, int bufByte) {
        const _Float16* as = wpk + (size_t)(sid * 2 + gy) * 16384;
#pragma unroll
        for (int rr = 0; rr < 4; ++rr)
            gll16(as + (size_t)(rr * 512 + tid) * 8, ldsb + bufByte + dstA[rr]);
        const int tap = sid / SPT;                 // SPT pow2 -> shift
        const int ci0 = (sid & (SPT - 1)) * 64;
        const int delta = ((tap / 3 - 1) * 128 + (tap % 3 - 1)) * CIN + ci0;
#pragma unroll
        for (int rr = 0; rr < 4; ++rr) {
            const bool ok = (inbm >> (rr * 9 + tap)) & 1ull;
            const _Float16* src = ok ? (bptr[rr] + delta) : zpage;
            gll16(src, ldsb + bufByte + dstB[rr]);
        }
    };

    f32x4 acc[8][4];
#pragma unroll
    for (int m = 0; m < 8; ++m)
#pragma unroll
        for (int n = 0; n < 4; ++n)
            acc[m][n] = (f32x4){0.f, 0.f, 0.f, 0.f};

    // K-step sequence i -> sid = tap(i)*SPT + cb(i), cb = i/9, tap = i%9
    // (ci-block-major: same activation lines reused 9 consecutive steps)
    STAGE(0, 0);          // i=0: (cb0,tap0) -> sid 0
    STAGE(SPT, 65536);    // i=1: (cb0,tap1) -> sid SPT
    int cb2 = 0, tap2 = 2;  // position of i=2 (NT >= 9 always here)

    for (int i = 0; i < NT; ++i) {
        // wait own step-i loads (keep i+1's 8 in flight); last iter drains.
        if (i < NT - 1) asm volatile("s_waitcnt vmcnt(8)" ::: "memory");
        else            asm volatile("s_waitcnt vmcnt(0)" ::: "memory");
        __builtin_amdgcn_sched_barrier(0);
        __builtin_amdgcn_s_barrier();       // all waves' step-i loads done
        __builtin_amdgcn_sched_barrier(0);

        const int ab = (i & 1) * 65536;
        __builtin_amdgcn_s_setprio(1);
#pragma unroll
        for (int s = 0; s < 2; ++s) {
            f16x8 bfr[4];
#pragma unroll
            for (int n = 0; n < 4; ++n) {
                const int row = wpx + n * 16 + lm;
                const int ch = (s * 4 + lu) ^ (row & 7);
                bfr[n] = *reinterpret_cast<const f16x8*>(ldsb + ab + 32768 + row * 128 + ch * 16);
            }
#pragma unroll
            for (int m = 0; m < 8; ++m) {
                const int row = wco + m * 16 + lm;
                const int ch = (s * 4 + lu) ^ (row & 7);
                const f16x8 afr = *reinterpret_cast<const f16x8*>(ldsb + ab + row * 128 + ch * 16);
#pragma unroll
                for (int n = 0; n < 4; ++n)
                    acc[m][n] = __builtin_amdgcn_mfma_f32_16x16x32_f16(afr, bfr[n], acc[m][n], 0, 0, 0);
            }
        }
        __builtin_amdgcn_s_setprio(0);
        __builtin_amdgcn_sched_barrier(0);
        __builtin_amdgcn_s_barrier();       // all waves done reading buf ab
        __builtin_amdgcn_sched_barrier(0);

        if (i + 2 < NT) {                   // overwrite buf ab with step i+2
            STAGE(tap2 * SPT + cb2, ab);
            if (++tap2 == 9) { tap2 = 0; ++cb2; }
        }
    }

    const int* mp = fg + img * 16384;
    _Float16* op = outp + (size_t)img * 16384 * 512;
#pragma unroll
    for (int n = 0; n < 4; ++n) {
        const int px = wpx + n * 16 + lm;
        const int y = y0 + (px >> 4), x = x0 + (px & 15);
        const float mv = (mp[y * 128 + x] > 0) ? 1.f : 0.f;
        _Float16* pp = op + (size_t)(y * 128 + x) * 512 + co0 + wco;
#pragma unroll
        for (int m = 0; m < 8; ++m) {
            const f32x4 bv = *reinterpret_cast<const f32x4*>(bias + co0 + wco + m * 16 + lu * 4);
            f16x4 h;
#pragma unroll
            for (int rr = 0; rr < 4; ++rr)
                h[rr] = (_Float16)(fmaxf(acc[m][n][rr] + bv[rr], 0.f) * mv);
            *reinterpret_cast<f16x4*>(pp + m * 16 + lu * 4) = h;
        }
    }
}

// ---------------------------------------------------------------------------
// fp16 NHWC 2x bilinear upsample (align_corners=False -> clamped 0.75/0.25).
// ---------------------------------------------------------------------------
__global__ void up2h_kernel(const _Float16* __restrict__ in, _Float16* __restrict__ out,
                            int Hin, int Win)
{
    const int Wout = Win << 1, Hout = Hin << 1;
    const int lw = __ffs(Wout) - 1, lh = __ffs(Hout) - 1;
    int i = blockIdx.x * THREADS + threadIdx.x;
    if (i >= 4 * Hout * Wout * 32) return;
    int u = i & 31;
    int p = i >> 5;
    int x = p & (Wout - 1);
    int y = (p >> lw) & (Hout - 1);
    int n = p >> (lw + lh);
    int iy = y >> 1, ix = x >> 1;
    int y2 = (y & 1) ? min(iy + 1, Hin - 1) : max(iy - 1, 0);
    int x2 = (x & 1) ? min(ix + 1, Win - 1) : max(ix - 1, 0);
    const _Float16* base = in + ((size_t)n * Hin * Win) * 256 + u * 8;
    f16x8 v00 = *reinterpret_cast<const f16x8*>(base + (iy * Win + ix) * 256);
    f16x8 v01 = *reinterpret_cast<const f16x8*>(base + (iy * Win + x2) * 256);
    f16x8 v10 = *reinterpret_cast<const f16x8*>(base + (y2 * Win + ix) * 256);
    f16x8 v11 = *reinterpret_cast<const f16x8*>(base + (y2 * Win + x2) * 256);
    f16x8 o;
#pragma unroll
    for (int j = 0; j < 8; ++j) {
        float v = 0.5625f * (float)v00[j] + 0.1875f * ((float)v01[j] + (float)v10[j])
                + 0.0625f * (float)v11[j];
        o[j] = (_Float16)v;
    }
    *reinterpret_cast<f16x8*>(out + (((size_t)n * Hout * Wout) + y * Wout + x) * 256 + u * 8) = o;
}

// fp32 NHWC 64^2 -> 128^2 upsample-ADD into Xc (stride 288, channels 0..255).
__global__ void up2add_kernel(const float* __restrict__ in, float* __restrict__ Xc)
{
    int i = blockIdx.x * THREADS + threadIdx.x;
    if (i >= 4 * 16384 * 32) return;
    int u = i & 31;
    int p = i >> 5;
    int x = p & 127;
    int y = (p >> 7) & 127;
    int n = p >> 14;
    int iy = y >> 1, ix = x >> 1;
    int y2 = (y & 1) ? min(iy + 1, 63) : max(iy - 1, 0);
    int x2 = (x & 1) ? min(ix + 1, 63) : max(ix - 1, 0);
    const float* base = in + ((size_t)n * 4096) * 256 + u * 8;
    f32x8 v00 = *reinterpret_cast<const f32x8*>(base + (iy * 64 + ix) * 256);
    f32x8 v01 = *reinterpret_cast<const f32x8*>(base + (iy * 64 + x2) * 256);
    f32x8 v10 = *reinterpret_cast<const f32x8*>(base + (y2 * 64 + ix) * 256);
    f32x8 v11 = *reinterpret_cast<const f32x8*>(base + (y2 * 64 + x2) * 256);
    float* dst = Xc + ((size_t)n * 16384 + y * 128 + x) * 288 + u * 8;
    f32x8 d = *reinterpret_cast<const f32x8*>(dst);
#pragma unroll
    for (int j = 0; j < 8; ++j)
        d[j] += 0.5625f * v00[j] + 0.1875f * (v01[j] + v10[j]) + 0.0625f * v11[j];
    *reinterpret_cast<f32x8*>(dst) = d;
}

// Coords into Xc channels 256..259; zero channels 260..287.
__global__ void coords2_kernel(const float* __restrict__ rel, const float* __restrict__ abs_,
                               float* __restrict__ Xc)
{
    int i = blockIdx.x * THREADS + threadIdx.x;
    if (i >= 4 * 16384) return;
    int px = i & 16383;
    int n = i >> 14;
    float* dst = Xc + ((size_t)n * 16384 + px) * 288 + 256;
    dst[0] = rel[((size_t)n * 2 + 0) * 16384 + px];
    dst[1] = rel[((size_t)n * 2 + 1) * 16384 + px];
    dst[2] = abs_[((size_t)n * 2 + 0) * 16384 + px];
    dst[3] = abs_[((size_t)n * 2 + 1) * 16384 + px];
#pragma unroll
    for (int c = 4; c < 32; ++c) dst[c] = 0.f;
}

// 1x1 predictor: NHWC fp16 [n][16384][512] -> NCHW fp32 [n][75][16384].
__global__ __launch_bounds__(256)
void predh_kernel(const _Float16* __restrict__ in, const float* __restrict__ w,
                  const float* __restrict__ bias, float* __restrict__ out)
{
    __shared__ _Float16 lw[25 * 512];
    const int co0 = blockIdx.y * 25;
    const int n = blockIdx.z;
    for (int idx = threadIdx.x; idx < 25 * 512; idx += 256)
        lw[idx] = (_Float16)w[(size_t)(co0 + idx / 512) * 512 + (idx & 511)];
    __syncthreads();
    int px = blockIdx.x * 256 + threadIdx.x;
    const _Float16* ip = in + ((size_t)n * 16384 + px) * 512;
    float acc[25];
#pragma unroll
    for (int j = 0; j < 25; ++j) acc[j] = bias[co0 + j];
    for (int g = 0; g < 64; ++g) {
        union { f16x8 v; f16x2 p[4]; } xv;
        xv.v = *reinterpret_cast<const f16x8*>(ip + g * 8);
#pragma unroll
        for (int j = 0; j < 25; ++j) {
            union { f16x8 v; f16x2 p[4]; } wv;
            wv.v = *reinterpret_cast<const f16x8*>(&lw[j * 512 + g * 8]);
#if __has_builtin(__builtin_amdgcn_fdot2)
#pragma unroll
            for (int k = 0; k < 4; ++k)
                acc[j] = __builtin_amdgcn_fdot2(xv.p[k], wv.p[k], acc[j], false);
#else
#pragma unroll
            for (int k = 0; k < 8; ++k)
                acc[j] = fmaf((float)xv.v[k], (float)wv.v[k], acc[j]);
#endif
        }
    }
    float* op = out + ((size_t)n * 75) * 16384 + px;
#pragma unroll
    for (int j = 0; j < 25; ++j)
        op[(size_t)(co0 + j) * 16384] = acc[j];
}

extern "C" void kernel_launch(void* const* d_in, const int* in_sizes, int n_in,
                              void* d_out, int out_size, void* d_ws, size_t ws_size,
                              hipStream_t stream)
{
    const float* p2   = (const float*)d_in[0];
    const float* p3   = (const float*)d_in[1];
    const float* p4   = (const float*)d_in[2];
    const float* p5   = (const float*)d_in[3];
    const float* rel  = (const float*)d_in[4];
    const float* abs_ = (const float*)d_in[5];
    const int*   fg   = (const int*)d_in[6];
    const float* w_p2_0 = (const float*)d_in[7];
    const float* b_p2_0 = (const float*)d_in[8];
    const float* w_p3_0 = (const float*)d_in[9];
    const float* b_p3_0 = (const float*)d_in[10];
    const float* w_p4_0 = (const float*)d_in[11];
    const float* b_p4_0 = (const float*)d_in[12];
    const float* w_p4_1 = (const float*)d_in[13];
    const float* b_p4_1 = (const float*)d_in[14];
    const float* w_p5_0 = (const float*)d_in[15];
    const float* b_p5_0 = (const float*)d_in[16];
    const float* w_p5_1 = (const float*)d_in[17];
    const float* b_p5_1 = (const float*)d_in[18];
    const float* w_p5_2 = (const float*)d_in[19];
    const float* b_p5_2 = (const float*)d_in[20];
    const float* comb_w = (const float*)d_in[21];
    const float* comb_b = (const float*)d_in[22];
    const float* head_w0 = (const float*)d_in[23];
    const float* head_b0 = (const float*)d_in[24];
    const float* head_w  = (const float*)d_in[25];
    const float* head_b  = (const float*)d_in[26];
    const float* pred_w  = (const float*)d_in[27];
    const float* pred_b  = (const float*)d_in[28];

    // Workspace layout (float offsets). Total ~57.1M floats = 228.4 MB.
    float* ws = (float*)d_ws;
    float*    Xc      = ws;                                  // 18,874,368
    _Float16* pingA   = (_Float16*)ws;                       // aliases Xc (dead after comb)
    _Float16* pingB   = (_Float16*)(ws + 18874368);          // 16,777,216
    float*    regD    = ws + 35651584;                       //  8,388,608
    _Float16* p2h     = (_Float16*)regD;
    _Float16* combOut = (_Float16*)regD;
    float*    t64sum  = regD;
    _Float16* t64b    = (_Float16*)(regD + 4194304);
    _Float16* t64c    = (_Float16*)(regD + 5242880);
    _Float16* t32a    = (_Float16*)(regD + 6291456);
    _Float16* t32b    = (_Float16*)(regD + 6553600);
    _Float16* t32c    = (_Float16*)(regD + 6815744);
    _Float16* t16a    = (_Float16*)(regD + 7077888);
    _Float16* p3h     = (_Float16*)(ws + 44040192);          //  2,097,152
    _Float16* p4h     = (_Float16*)(ws + 46137344);          //    524,288
    _Float16* p5h     = (_Float16*)(ws + 46661632);          //    131,072
    _Float16* wpScale = (_Float16*)(ws + 46792704);          //  1,441,792
    float*    zpage   = ws + 48234496;                       //      1,024 (4 KB zeros)
    _Float16* wpH0    = (_Float16*)(ws + 48235520);          //    589,824 (1,179,648 f16)
    _Float16* wpH     = (_Float16*)(ws + 48825344);          //  8,257,536 (7 x 2,359,296 f16)

    auto packw = [&](const float* w, _Float16* dst, int Cin, int Cout) {
        int CCl = (Cin + 31) / 32;
        int total = Cout * CCl * 4;
        pack_w16_kernel<<<dim3((total + THREADS - 1) / THREADS), dim3(THREADS), 0, stream>>>(
            w, dst, Cin, Cout, CCl);
    };
    auto transp = [&](const float* in, _Float16* out, int C, int HW) {
        t_kernel<<<dim3(HW / 64, C / 32, 4), dim3(256), 0, stream>>>(in, out, C, HW);
    };
    auto convu = [&](const void* in, const _Float16* wpk, const float* bs, void* outp,
                     int inf32, int outmode, int Cout, int H, int W,
                     int inCst, int outCst, int useMask) {
        dim3 grid((W / 16) * (H / 16), Cout / 128, 4);
        dim3 blk(512);
        if (inf32 == 0 && outmode == 0)
            convu_kernel<0, 0, 8><<<grid, blk, 0, stream>>>(in, wpk, bs, fg, outp, Cout, H, W, inCst, outCst, useMask);
        else if (inf32 == 0 && outmode == 1)
            convu_kernel<0, 1, 8><<<grid, blk, 0, stream>>>(in, wpk, bs, fg, outp, Cout, H, W, inCst, outCst, useMask);
        else if (inf32 == 0 && outmode == 2)
            convu_kernel<0, 2, 8><<<grid, blk, 0, stream>>>(in, wpk, bs, fg, outp, Cout, H, W, inCst, outCst, useMask);
        else
            convu_kernel<1, 0, 9><<<grid, blk, 0, stream>>>(in, wpk, bs, fg, outp, Cout, H, W, inCst, outCst, useMask);
    };
    auto up2h = [&](const _Float16* in, _Float16* out, int Hin, int Win) {
        int total = 4 * (Hin * 2) * (Win * 2) * 32;
        up2h_kernel<<<dim3((total + THREADS - 1) / THREADS), dim3(THREADS), 0, stream>>>(
            in, out, Hin, Win);
    };

    // ---- zero-page + pack head weights (GEMM format, persistent) ----
    zerows_kernel<<<dim3(4), dim3(THREADS), 0, stream>>>(zpage);
    pack_whead_kernel<<<dim3(576), dim3(THREADS), 0, stream>>>(head_w0, wpH0, 256);
    for (int i = 0; i < 7; ++i)
        pack_whead_kernel<<<dim3(1152), dim3(THREADS), 0, stream>>>(
            head_w + (size_t)i * 2359296, wpH + (size_t)i * 2359296, 512);

    // ---- transpose FPN inputs to NHWC fp16 ----
    transp(p2, p2h, 256, 16384);
    transp(p3, p3h, 256, 4096);
    transp(p4, p4h, 256, 1024);
    transp(p5, p5h, 256, 256);

    // ---- p2 scale head -> Xc (fp32 NHWC-288), coords+zeropad ----
    packw(w_p2_0, wpScale, 256, 256);
    convu(p2h, wpScale, b_p2_0, Xc, 0, 1, 256, 128, 128, 256, 288, 0);
    coords2_kernel<<<dim3(256), dim3(THREADS), 0, stream>>>(rel, abs_, Xc);

    // ---- p3 -> t64sum (write) ----
    packw(w_p3_0, wpScale, 256, 256);
    convu(p3h, wpScale, b_p3_0, t64sum, 0, 1, 256, 64, 64, 256, 256, 0);

    // ---- p4 chain: conv32 -> up -> conv64 (add into t64sum) ----
    packw(w_p4_0, wpScale, 256, 256);
    convu(p4h, wpScale, b_p4_0, t32a, 0, 0, 256, 32, 32, 256, 256, 0);
    up2h(t32a, t64b, 32, 32);
    packw(w_p4_1, wpScale, 256, 256);
    convu(t64b, wpScale, b_p4_1, t64sum, 0, 2, 256, 64, 64, 256, 256, 0);

    // ---- p5 chain: conv16 -> up -> conv32 -> up -> conv64 (add) ----
    packw(w_p5_0, wpScale, 256, 256);
    convu(p5h, wpScale, b_p5_0, t16a, 0, 0, 256, 16, 16, 256, 256, 0);
    up2h(t16a, t32b, 16, 16);
    packw(w_p5_1, wpScale, 256, 256);
    convu(t32b, wpScale, b_p5_1, t32c, 0, 0, 256, 32, 32, 256, 256, 0);
    up2h(t32c, t64c, 32, 32);
    packw(w_p5_2, wpScale, 256, 256);
    convu(t64c, wpScale, b_p5_2, t64sum, 0, 2, 256, 64, 64, 256, 256, 0);

    // ---- single upsample-add of merged 64^2 sum into Xc ----
    up2add_kernel<<<dim3(8192), dim3(THREADS), 0, stream>>>(t64sum, Xc);

    // ---- comb conv (Xc fp32 NHWC-288 -> combOut fp16 NHWC-256), relu+mask ----
    packw(comb_w, wpScale, 260, 256);
    convu(Xc, wpScale, comb_b, combOut, 1, 0, 256, 128, 128, 288, 256, 1);

    // ---- head chain: 256^2-tile LDS-staged GEMM convs, batched ----
    gemm_head_kernel<256><<<dim3(512), dim3(512), 0, stream>>>(
        combOut, wpH0, head_b0, fg, pingA, (const _Float16*)zpage);
    {
        const _Float16* s = pingA;
        _Float16* d = pingB;
        for (int i = 0; i < 7; ++i) {
            gemm_head_kernel<512><<<dim3(512), dim3(512), 0, stream>>>(
                s, wpH + (size_t)i * 2359296, head_b + (size_t)i * 512, fg, d,
                (const _Float16*)zpage);
            _Float16* tmp = (_Float16*)s; s = d; d = tmp;
        }
    }

    // ---- predictor (reads pingB), batched ----
    predh_kernel<<<dim3(64, 3, 4), dim3(256), 0, stream>>>(pingB, pred_w, pred_b, (float*)d_out);
}